// Round 9
// baseline (2766.847 us; speedup 1.0000x reference)
//
#include <hip/hip_runtime.h>
#include <cmath>

#ifndef M_PI
#define M_PI 3.14159265358979323846
#endif

#define T_LEN   160000
#define NSEG    155
#define ROWS    32
#define NBANDS  8

#define CHUNK   64
#define NQ      16                   // float4 quads per chunk
#define NCHUNK  2496                 // 64*2496 = 159744 = all samples any segment uses
#define TOT_IT  (NCHUNK + 2)         // 3-stage pipeline drain
#define LOUD_FLOATS (NBANDS * 2 * ROWS * NSEG)   // 79360

struct AllCoefs {
    float h[NBANDS][5];   // b0 b1 b2 a1 a2 (a0-normalized, f32-cast like np.float32)
    float l[NBANDS][5];
};

// Workgroup barrier WITHOUT the vmcnt(0) drain __syncthreads() forces.
// Only LDS (lgkmcnt) carries inter-wave data in this kernel; w0's global
// prefetch loads are wave-private registers and may stay in flight across
// the barrier (this was the ~900-cyc/iter HBM-latency stall in R4-R8).
__device__ __forceinline__ void barrier_lds_only() {
    asm volatile("s_waitcnt lgkmcnt(0)\n\ts_barrier" ::: "memory");
}

// ============================ Fused pipeline =============================
// One block per (band, src): 32 chains, 3 waves (192 thr) on 3 of the CU's
// 4 SIMDs:
//   w0 : hpFIR + hpREC   global x (distance-2 reg prefetch) -> I1
//   w1 : lpFIR + lpREC   I1 -> I2
//   w2 : weighting, dual parity: lanes 0-31 even segments, 32-63 odd
// Interfaces: float4 [quad][chain] -> ds b128, conflict-free.
// Every per-chain arithmetic op is identical, in identical order, to the
// R3/R7/R8 kernel verified BIT-EXACT vs the np reference (absmax 0.0).
__global__ __launch_bounds__(192, 1)
void tf_pipe3_kernel(const float* __restrict__ sig, const float* __restrict__ wm,
                     float* __restrict__ loud, AllCoefs C) {
    __shared__ float I1[2][CHUNK * 32];   // hp -> lp       (32 KiB)
    __shared__ float I2[2][CHUNK * 32];   // lp -> weight   (32 KiB)

    const int band = blockIdx.x;
    const int src  = blockIdx.y;              // 0 = signal, 1 = watermark
    const int tid  = threadIdx.x;
    const int wid  = tid >> 6;
    const int lane = tid & 63;
    const int ch   = lane & 31;               // chain = batch row

    const float hb0 = C.h[band][0], hb1 = C.h[band][1], hb2 = C.h[band][2];
    const float hna1 = -C.h[band][3], hna2 = -C.h[band][4];
    const float lb0 = C.l[band][0], lb1 = C.l[band][1], lb2 = C.l[band][2];
    const float lna1 = -C.l[band][3], lna2 = -C.l[band][4];
    const float NA1 =  1.79999995231628417969f; // -np.float32(-1.8)
    const float NA2 = -0.810000002384185791f;   // -np.float32(0.81)

    const float* __restrict__ xrow = (src ? wm : sig) + (size_t)ch * T_LEN;

    float x1 = 0.f, x2 = 0.f, y1 = 0.f, y2 = 0.f, acc = 0.f;

    float4 pfA[NQ], pfB[NQ];                  // distance-2 prefetch, constant-indexed
    if (wid == 0 && lane < 32) {
        const float4* p0 = (const float4*)xrow;
        #pragma unroll
        for (int i = 0; i < NQ; ++i) pfA[i] = p0[i];            // chunk 0
        #pragma unroll
        for (int i = 0; i < NQ; ++i) pfB[i] = p0[NQ + i];       // chunk 1
    }

// hpFIR+hpREC: compute chunk cc from USE[], refill USE[] with chunk cc+2
// (max addr (2495+2)*64+63 = 159871 < 160000, in-bounds). Loads get ~2 full
// iterations in flight; the raw barrier never drains them.
#define HP1(xx, oo)                                                          \
    {  float s1 = __fmaf_rn(hb0, xx, __fmul_rn(hb1, x1));                    \
       float s2 = __fmaf_rn(hb2, x2, s1); x2 = x1; x1 = xx;                  \
       float s3 = __fmaf_rn(hna1, y1, s2);                                   \
       oo = __fmaf_rn(hna2, y2, s3); y2 = y1; y1 = oo; }
#define W0_BODY(USE, cc)                                                     \
    {                                                                        \
        const float4* __restrict__ nx =                                      \
            (const float4*)(xrow + (size_t)((cc) + 2) * CHUNK);              \
        float4* __restrict__ ob = (float4*)I1[(cc) & 1];                     \
        _Pragma("unroll")                                                    \
        for (int i = 0; i < NQ; ++i) {                                       \
            float4 v = USE[i];                                               \
            USE[i] = nx[i];                                                  \
            float4 o;                                                        \
            HP1(v.x, o.x) HP1(v.y, o.y) HP1(v.z, o.z) HP1(v.w, o.w)          \
            ob[i * 32 + ch] = o;                                             \
        }                                                                    \
    }

    for (int iter = 0; iter < TOT_IT; ++iter) {
        if (wid == 0) {
            if (iter < NCHUNK && lane < 32) {
                const int c = iter;
                if ((c & 1) == 0) W0_BODY(pfA, c)
                else              W0_BODY(pfB, c)
            }
        } else if (wid == 1) {
            if (iter >= 1 && iter <= NCHUNK && lane < 32) {
                const int c = iter - 1;
                const float4* __restrict__ ib = (const float4*)I1[c & 1];
                float4* __restrict__ ob = (float4*)I2[c & 1];
                float4 v[NQ];
                #pragma unroll
                for (int i = 0; i < NQ; ++i) v[i] = ib[i * 32 + ch];
                #pragma unroll
                for (int i = 0; i < NQ; ++i) {
                    float4 o;
                    #define LP1(xx, oo) \
                        { float s1 = __fmaf_rn(lb0, xx, __fmul_rn(lb1, x1)); \
                          float s2 = __fmaf_rn(lb2, x2, s1); x2 = x1; x1 = xx; \
                          float s3 = __fmaf_rn(lna1, y1, s2); \
                          oo = __fmaf_rn(lna2, y2, s3); y2 = y1; y1 = oo; }
                    LP1(v[i].x, o.x) LP1(v[i].y, o.y) LP1(v[i].z, o.z) LP1(v[i].w, o.w)
                    #undef LP1
                    ob[i * 32 + ch] = o;
                }
            }
        } else {
            if (iter >= 2) {
                const int c = iter - 2;
                const bool evenHalf = (lane < 32);
                const int m32 = c & 31;
                // segment j = c/16 starts at chunk c when c%32==0 (even j) or 16 (odd j)
                if ((m32 == (evenHalf ? 0 : 16)) && (c >> 4) < NSEG) {
                    x1 = 0.f; x2 = 0.f; y1 = 0.f; y2 = 0.f; acc = 0.f;
                }
                const float4* __restrict__ ib = (const float4*)I2[c & 1];
                float4 v[NQ];
                #pragma unroll
                for (int i = 0; i < NQ; ++i) v[i] = ib[i * 32 + ch]; // halves broadcast
                #pragma unroll
                for (int i = 0; i < NQ; ++i) {
                    float s1, s2, s3, yy;
                    // s1 = fma(-2,x1,x): product exact -> bit-identical to add form
                    #define WSTEP(xx) \
                        s1 = __fmaf_rn(-2.0f, x1, xx); \
                        s2 = __fadd_rn(s1, x2); \
                        s3 = __fmaf_rn(NA1, y1, s2); \
                        yy = __fmaf_rn(NA2, y2, s3); \
                        x2 = x1; x1 = xx; y2 = y1; y1 = yy; \
                        acc = __fmaf_rn(yy, yy, acc);
                    WSTEP(v[i].x) WSTEP(v[i].y) WSTEP(v[i].z) WSTEP(v[i].w)
                    #undef WSTEP
                }
                // even seg ends when c%32==31; odd seg when c%32==15 (c>=31); j=(c-31)/16
                const int endm = evenHalf ? 31 : 15;
                if (m32 == endm && c >= 31) {
                    const int j = (c - 31) >> 4;
                    float e = __fmul_rn(acc, 0.00048828125f);   // /2048 exact
                    loud[((size_t)((band * 2 + src) * ROWS + ch)) * NSEG + j] =
                        __fmul_rn(10.0f, log10f(__fadd_rn(e, 1e-8f)));
                }
            }
        }
        barrier_lds_only();
    }
#undef W0_BODY
#undef HP1
}

__global__ __launch_bounds__(256)
void tf_reduce_kernel(const float* __restrict__ loud, float* __restrict__ out) {
    __shared__ double sh[256];
    const int per_band = ROWS * NSEG;       // 4960
    const int npairs   = NBANDS * per_band; // 39680
    double s = 0.0;
    for (int idx = threadIdx.x; idx < npairs; idx += 256) {
        int band = idx / per_band;
        int rs   = idx - band * per_band;
        float a = loud[(size_t)(band * 2 + 0) * per_band + rs];
        float b = loud[(size_t)(band * 2 + 1) * per_band + rs];
        s += fabs((double)b - (double)a);
    }
    sh[threadIdx.x] = s;
    __syncthreads();
    for (int off = 128; off > 0; off >>= 1) {
        if (threadIdx.x < off) sh[threadIdx.x] += sh[threadIdx.x + off];
        __syncthreads();
    }
    if (threadIdx.x == 0) out[0] = (float)(sh[0] / (double)npairs);
}

// Host-side coefficients: f64 with the reference's exact expression order,
// then cast each to f32 (mirrors tuple(np.float32(v / a0) ...)).
static void mk_hp(double cutoff, float* o) {
    const double w0    = 2.0 * M_PI * cutoff / 16000.0;
    const double alpha = sin(w0) / (2.0 * 0.707);
    const double cw    = cos(w0);
    const double b0 = (1.0 + cw) / 2.0;
    const double b1 = -(1.0 + cw);
    const double b2 = (1.0 + cw) / 2.0;
    const double a0 = 1.0 + alpha;
    const double a1 = -2.0 * cw;
    const double a2 = 1.0 - alpha;
    o[0] = (float)(b0 / a0); o[1] = (float)(b1 / a0); o[2] = (float)(b2 / a0);
    o[3] = (float)(a1 / a0); o[4] = (float)(a2 / a0);
}

static void mk_lp(double cutoff, float* o) {
    const double w0    = 2.0 * M_PI * cutoff / 16000.0;
    const double alpha = sin(w0) / (2.0 * 0.707);
    const double cw    = cos(w0);
    const double b0 = (1.0 - cw) / 2.0;
    const double b1 = 1.0 - cw;
    const double b2 = (1.0 - cw) / 2.0;
    const double a0 = 1.0 + alpha;
    const double a1 = -2.0 * cw;
    const double a2 = 1.0 - alpha;
    o[0] = (float)(b0 / a0); o[1] = (float)(b1 / a0); o[2] = (float)(b2 / a0);
    o[3] = (float)(a1 / a0); o[4] = (float)(a2 / a0);
}

extern "C" void kernel_launch(void* const* d_in, const int* in_sizes, int n_in,
                              void* d_out, int out_size, void* d_ws, size_t ws_size,
                              hipStream_t stream) {
    const float* sig = (const float*)d_in[0];
    const float* wm  = (const float*)d_in[1];
    float* loud = (float*)d_ws;   // 79360 floats = 310 KiB

    AllCoefs C;
    for (int i = 0; i < NBANDS; ++i) {
        mk_hp(1000.0 * (double)i,       C.h[i]);   // low_cut  = i*1000 exactly
        mk_lp(1000.0 * (double)(i + 1), C.l[i]);   // high_cut = (i+1)*1000 exactly
    }

    tf_pipe3_kernel<<<dim3(NBANDS, 2), 192, 0, stream>>>(sig, wm, loud, C);
    tf_reduce_kernel<<<1, 256, 0, stream>>>(loud, (float*)d_out);
}

// Round 10
// 2191.568 us; speedup vs baseline: 1.2625x; 1.2625x over previous
//
#include <hip/hip_runtime.h>
#include <cmath>

#ifndef M_PI
#define M_PI 3.14159265358979323846
#endif

#define T_LEN   160000
#define NSEG    155
#define ROWS    32
#define NBANDS  8

#define CHUNK   256                  // samples per barrier interval
#define NSUB    4                    // sub-chunks of 64
#define NQ      16                   // float4 quads per sub-chunk
#define QPC     64                   // quads per chunk
#define NCHUNK  624                  // 256*624 = 159744 = all samples any segment uses
#define TOT_IT  (NCHUNK + 2)         // 3-stage pipeline drain
#define LOUD_FLOATS (NBANDS * 2 * ROWS * NSEG)   // 79360

struct AllCoefs {
    float h[NBANDS][5];   // b0 b1 b2 a1 a2 (a0-normalized, f32-cast like np.float32)
    float l[NBANDS][5];
};

// Workgroup barrier without the vmcnt(0) drain (only LDS carries inter-wave
// data; w0's global prefetch stays in flight across the barrier).
__device__ __forceinline__ void barrier_lds_only() {
    asm volatile("s_waitcnt lgkmcnt(0)\n\ts_barrier" ::: "memory");
}

// ============================ Fused pipeline =============================
// One block per (band, src): 32 chains, 3 waves. 256 samples per barrier
// (4 sub-chunks of 64) to amortize the ~1650-cyc fixed per-barrier cost
// measured invariant across R4-R9:
//   w0 : hpFIR + hpREC   global x (sub-chunk ping-pong prefetch) -> I1
//   w1 : lpFIR + lpREC   I1 -> I2
//   w2 : weighting, dual parity: lanes 0-31 even segments, 32-63 odd
// Interfaces: float4 [quad][chain] -> ds b128, conflict-free.
// Every per-chain arithmetic op is identical, in identical order, to the
// R3/R7/R8/R9 kernel verified BIT-EXACT vs the np reference (absmax 0.0).
__global__ __launch_bounds__(192, 1)
void tf_pipe3_kernel(const float* __restrict__ sig, const float* __restrict__ wm,
                     float* __restrict__ loud, AllCoefs C) {
    __shared__ float I1[2][CHUNK * 32];   // hp -> lp       (64 KiB)
    __shared__ float I2[2][CHUNK * 32];   // lp -> weight   (64 KiB)

    const int band = blockIdx.x;
    const int src  = blockIdx.y;              // 0 = signal, 1 = watermark
    const int tid  = threadIdx.x;
    const int wid  = tid >> 6;
    const int lane = tid & 63;
    const int ch   = lane & 31;               // chain = batch row

    const float hb0 = C.h[band][0], hb1 = C.h[band][1], hb2 = C.h[band][2];
    const float hna1 = -C.h[band][3], hna2 = -C.h[band][4];
    const float lb0 = C.l[band][0], lb1 = C.l[band][1], lb2 = C.l[band][2];
    const float lna1 = -C.l[band][3], lna2 = -C.l[band][4];
    const float NA1 =  1.79999995231628417969f; // -np.float32(-1.8)
    const float NA2 = -0.810000002384185791f;   // -np.float32(0.81)

    const float* __restrict__ xrow = (src ? wm : sig) + (size_t)ch * T_LEN;
    const float4* __restrict__ xq  = (const float4*)xrow;   // global quad array

    float x1 = 0.f, x2 = 0.f, y1 = 0.f, y2 = 0.f, acc = 0.f;

    float4 pfA[NQ], pfB[NQ];                  // sub-chunk ping-pong prefetch
    if (wid == 0 && lane < 32) {
        #pragma unroll
        for (int i = 0; i < NQ; ++i) pfA[i] = xq[i];   // chunk 0, sub 0
    }

#define HP1(xx, oo)                                                          \
    {  float s1 = __fmaf_rn(hb0, xx, __fmul_rn(hb1, x1));                    \
       float s2 = __fmaf_rn(hb2, x2, s1); x2 = x1; x1 = xx;                  \
       float s3 = __fmaf_rn(hna1, y1, s2);                                   \
       oo = __fmaf_rn(hna2, y2, s3); y2 = y1; y1 = oo; }

// Consume USE (holds sub-chunk `s` of chunk `cc`), refill FILL from quad
// base NEXTQ (the next sub-chunk; for s=3 that's chunk cc+1 sub 0, loads
// stay in flight across the lds-only barrier).
#define W0SUB(USE, FILL, cc, s, NEXTQ)                                       \
    {                                                                        \
        float4* __restrict__ ob = (float4*)I1[(cc) & 1];                     \
        _Pragma("unroll")                                                    \
        for (int i = 0; i < NQ; ++i) {                                       \
            float4 v = USE[i];                                               \
            FILL[i] = xq[(NEXTQ) + i];                                       \
            float4 o;                                                        \
            HP1(v.x, o.x) HP1(v.y, o.y) HP1(v.z, o.z) HP1(v.w, o.w)          \
            ob[((s) * NQ + i) * 32 + ch] = o;                                \
        }                                                                    \
    }

    for (int iter = 0; iter < TOT_IT; ++iter) {
        if (wid == 0) {
            if (iter < NCHUNK && lane < 32) {
                const int c = iter;
                const int q0 = c * QPC;
                // invariant: pfA holds sub 0 of chunk c
                W0SUB(pfA, pfB, c, 0, q0 + 1 * NQ)
                W0SUB(pfB, pfA, c, 1, q0 + 2 * NQ)
                W0SUB(pfA, pfB, c, 2, q0 + 3 * NQ)
                W0SUB(pfB, pfA, c, 3, q0 + 4 * NQ)   // next chunk sub 0
                // max prefetch: c=623 -> quads 39936..39951 -> sample 159807 < 160000
            }
        } else if (wid == 1) {
            if (iter >= 1 && iter <= NCHUNK && lane < 32) {
                const int c = iter - 1;
                const float4* __restrict__ ib = (const float4*)I1[c & 1];
                float4* __restrict__ ob = (float4*)I2[c & 1];
                #pragma unroll
                for (int s = 0; s < NSUB; ++s) {
                    float4 v[NQ];
                    #pragma unroll
                    for (int i = 0; i < NQ; ++i) v[i] = ib[(s * NQ + i) * 32 + ch];
                    #pragma unroll
                    for (int i = 0; i < NQ; ++i) {
                        float4 o;
                        #define LP1(xx, oo) \
                            { float s1 = __fmaf_rn(lb0, xx, __fmul_rn(lb1, x1)); \
                              float s2 = __fmaf_rn(lb2, x2, s1); x2 = x1; x1 = xx; \
                              float s3 = __fmaf_rn(lna1, y1, s2); \
                              oo = __fmaf_rn(lna2, y2, s3); y2 = y1; y1 = oo; }
                        LP1(v[i].x, o.x) LP1(v[i].y, o.y) LP1(v[i].z, o.z) LP1(v[i].w, o.w)
                        #undef LP1
                        ob[(s * NQ + i) * 32 + ch] = o;
                    }
                }
            }
        } else {
            if (iter >= 2) {
                const int c = iter - 2;
                const bool evenHalf = (lane < 32);
                const float4* __restrict__ ib = (const float4*)I2[c & 1];
                #pragma unroll
                for (int s = 0; s < NSUB; ++s) {
                    const int u = c * NSUB + s;       // global 64-sample index
                    const int m32 = u & 31;
                    // segment j = u/16 starts at sub-chunk u when u%32==0 (even j) or 16 (odd j)
                    if ((m32 == (evenHalf ? 0 : 16)) && (u >> 4) < NSEG) {
                        x1 = 0.f; x2 = 0.f; y1 = 0.f; y2 = 0.f; acc = 0.f;
                    }
                    float4 v[NQ];
                    #pragma unroll
                    for (int i = 0; i < NQ; ++i) v[i] = ib[(s * NQ + i) * 32 + ch];
                    #pragma unroll
                    for (int i = 0; i < NQ; ++i) {
                        float s1, s2, s3, yy;
                        // s1 = fma(-2,x1,x): product exact -> bit-identical to add form
                        #define WSTEP(xx) \
                            s1 = __fmaf_rn(-2.0f, x1, xx); \
                            s2 = __fadd_rn(s1, x2); \
                            s3 = __fmaf_rn(NA1, y1, s2); \
                            yy = __fmaf_rn(NA2, y2, s3); \
                            x2 = x1; x1 = xx; y2 = y1; y1 = yy; \
                            acc = __fmaf_rn(yy, yy, acc);
                        WSTEP(v[i].x) WSTEP(v[i].y) WSTEP(v[i].z) WSTEP(v[i].w)
                        #undef WSTEP
                    }
                    // even seg ends when u%32==31; odd when u%32==15 (u>=31); j=(u-31)/16
                    const int endm = evenHalf ? 31 : 15;
                    if (m32 == endm && u >= 31) {
                        const int j = (u - 31) >> 4;
                        float e = __fmul_rn(acc, 0.00048828125f);   // /2048 exact
                        loud[((size_t)((band * 2 + src) * ROWS + ch)) * NSEG + j] =
                            __fmul_rn(10.0f, log10f(__fadd_rn(e, 1e-8f)));
                    }
                }
            }
        }
        barrier_lds_only();
    }
#undef W0SUB
#undef HP1
}

__global__ __launch_bounds__(256)
void tf_reduce_kernel(const float* __restrict__ loud, float* __restrict__ out) {
    __shared__ double sh[256];
    const int per_band = ROWS * NSEG;       // 4960
    const int npairs   = NBANDS * per_band; // 39680
    double s = 0.0;
    for (int idx = threadIdx.x; idx < npairs; idx += 256) {
        int band = idx / per_band;
        int rs   = idx - band * per_band;
        float a = loud[(size_t)(band * 2 + 0) * per_band + rs];
        float b = loud[(size_t)(band * 2 + 1) * per_band + rs];
        s += fabs((double)b - (double)a);
    }
    sh[threadIdx.x] = s;
    __syncthreads();
    for (int off = 128; off > 0; off >>= 1) {
        if (threadIdx.x < off) sh[threadIdx.x] += sh[threadIdx.x + off];
        __syncthreads();
    }
    if (threadIdx.x == 0) out[0] = (float)(sh[0] / (double)npairs);
}

// Host-side coefficients: f64 with the reference's exact expression order,
// then cast each to f32 (mirrors tuple(np.float32(v / a0) ...)).
static void mk_hp(double cutoff, float* o) {
    const double w0    = 2.0 * M_PI * cutoff / 16000.0;
    const double alpha = sin(w0) / (2.0 * 0.707);
    const double cw    = cos(w0);
    const double b0 = (1.0 + cw) / 2.0;
    const double b1 = -(1.0 + cw);
    const double b2 = (1.0 + cw) / 2.0;
    const double a0 = 1.0 + alpha;
    const double a1 = -2.0 * cw;
    const double a2 = 1.0 - alpha;
    o[0] = (float)(b0 / a0); o[1] = (float)(b1 / a0); o[2] = (float)(b2 / a0);
    o[3] = (float)(a1 / a0); o[4] = (float)(a2 / a0);
}

static void mk_lp(double cutoff, float* o) {
    const double w0    = 2.0 * M_PI * cutoff / 16000.0;
    const double alpha = sin(w0) / (2.0 * 0.707);
    const double cw    = cos(w0);
    const double b0 = (1.0 - cw) / 2.0;
    const double b1 = 1.0 - cw;
    const double b2 = (1.0 - cw) / 2.0;
    const double a0 = 1.0 + alpha;
    const double a1 = -2.0 * cw;
    const double a2 = 1.0 - alpha;
    o[0] = (float)(b0 / a0); o[1] = (float)(b1 / a0); o[2] = (float)(b2 / a0);
    o[3] = (float)(a1 / a0); o[4] = (float)(a2 / a0);
}

extern "C" void kernel_launch(void* const* d_in, const int* in_sizes, int n_in,
                              void* d_out, int out_size, void* d_ws, size_t ws_size,
                              hipStream_t stream) {
    const float* sig = (const float*)d_in[0];
    const float* wm  = (const float*)d_in[1];
    float* loud = (float*)d_ws;   // 79360 floats = 310 KiB

    AllCoefs C;
    for (int i = 0; i < NBANDS; ++i) {
        mk_hp(1000.0 * (double)i,       C.h[i]);   // low_cut  = i*1000 exactly
        mk_lp(1000.0 * (double)(i + 1), C.l[i]);   // high_cut = (i+1)*1000 exactly
    }

    tf_pipe3_kernel<<<dim3(NBANDS, 2), 192, 0, stream>>>(sig, wm, loud, C);
    tf_reduce_kernel<<<1, 256, 0, stream>>>(loud, (float*)d_out);
}